// Round 2
// baseline (101.680 us; speedup 1.0000x reference)
//
#include <hip/hip_runtime.h>

// Problem constants (fixed by reference)
constexpr int B = 4, T = 8, V = 256, F = 64;
constexpr int BT = B * T;            // 32 (b,t) slices
constexpr int CHUNK = 4;             // rows of i per block (R8: halved for TLP)
constexpr int NCHUNK = V / CHUNK;    // 64 -> grid = 32*64 = 2048 blocks (8 blocks/CU)
constexpr int K4 = F / 4;            // 16 float4 chunks per row

typedef float v2f __attribute__((ext_vector_type(2)));

// Block = (bt, 4-row chunk). Thread tid owns column j=tid.
// score(i,j) = sum_f |x_i[f]-x_j[f]|*a[f] is SYMMETRIC, so denom[i]
// (= column-i sum in the reference) equals the row-i sum -> block-local
// reduction, no grid sync / atomics / workspace.
//
// R5: row data via WAVE-UNIFORM global addresses -> s_load_dwordx4 (scalar
// pipe + scalar cache), no LDS staging.
// R6: packed-f32 inner loop (v_pk_sub / v_pk_max(neg) / v_pk_fma).
// R7 (REVERTED): transposed column stream was neutral on the kernel and
// cost a launch (+4.4us) -> column loads were never the bottleneck.
// R8: the stall is scalar-load latency with only 4 waves/SIMD to hide it.
//   (a) a[] no longer pinned in 64 VGPRs (af2 preload removed; a4[k] read
//       in-loop is wave-uniform -> SGPRs, the one scalar operand VOP3P allows)
//   (b) CHUNK 8->4: grid 2048 = 8 blocks/CU, doubling waves/SIMD
//   (c) __launch_bounds__(256,8) holds VGPR <= 64 so all 8 blocks fit.
__global__ __launch_bounds__(256, 8)
void gl_fused(const float* __restrict__ X, const float* __restrict__ A,
              float* __restrict__ OUT)
{
    const int tid = threadIdx.x;           // column j
    const int bt  = blockIdx.x / NCHUNK;
    const int ic  = blockIdx.x % NCHUNK;
    const int i0  = ic * CHUNK;

    const float* xbt = X + (size_t)bt * V * F;            // [256][64] tile
    const float4* xrow4 = reinterpret_cast<const float4*>(xbt + (size_t)i0 * F);
    // xrow4[r*K4 + k] = float4 of row i0+r, features 4k..4k+3 (uniform addr)
    const float4* a4 = reinterpret_cast<const float4*>(A); // uniform addr

    __shared__ float wpart[4][CHUNK];      // per-wave partial row sums
    __shared__ float rden[CHUNK];          // reciprocal denominators

    v2f acc2[CHUNK];
#pragma unroll
    for (int r = 0; r < CHUNK; ++r) acc2[r] = (v2f){0.0f, 0.0f};

    // stream own column in float4 chunks; CHUNK independent packed fma chains.
    const float4* colp = reinterpret_cast<const float4*>(xbt + (size_t)tid * F);
#pragma unroll
    for (int k = 0; k < K4; ++k) {
        const float4 xv = colp[k];
        const float4 av = a4[k];                    // uniform -> s_load, SGPRs
        const v2f xlo = (v2f){xv.x, xv.y};
        const v2f xhi = (v2f){xv.z, xv.w};
        const v2f alo = (v2f){av.x, av.y};
        const v2f ahi = (v2f){av.z, av.w};
#pragma unroll
        for (int r = 0; r < CHUNK; ++r) {
            const float4 sr = xrow4[r * K4 + k];    // uniform -> s_load_dwordx4
            const v2f d0 = xlo - (v2f){sr.x, sr.y}; // v_pk_add (neg mod)
            const v2f d1 = xhi - (v2f){sr.z, sr.w};
            const v2f a0 = __builtin_elementwise_max(d0, -d0);  // v_pk_max (neg mod)
            const v2f a1 = __builtin_elementwise_max(d1, -d1);
            acc2[r] = __builtin_elementwise_fma(a0, alo, acc2[r]); // v_pk_fma
            acc2[r] = __builtin_elementwise_fma(a1, ahi, acc2[r]);
        }
    }

    float tmp[CHUNK];
#pragma unroll
    for (int r = 0; r < CHUNK; ++r) {
        const float s = acc2[r].x + acc2[r].y;
        tmp[r] = __expf(fmaxf(s, 0.0f));
    }

    // block reduction: row sum = denominator (symmetry)
    const int lane = tid & 63;
    const int wv   = tid >> 6;
#pragma unroll
    for (int r = 0; r < CHUNK; ++r) {
        float v = tmp[r];
        v += __shfl_xor(v, 32);
        v += __shfl_xor(v, 16);
        v += __shfl_xor(v, 8);
        v += __shfl_xor(v, 4);
        v += __shfl_xor(v, 2);
        v += __shfl_xor(v, 1);
        if (lane == 0) wpart[wv][r] = v;
    }
    __syncthreads();
    if (tid < CHUNK) {
        const float d = wpart[0][tid] + wpart[1][tid] + wpart[2][tid] + wpart[3][tid];
        rden[tid] = 1.0f / d;
    }
    __syncthreads();

    // S[bt, i0+r, tid] = tmp[r] / denom[i0+r]; consecutive tids -> coalesced
    float* obase = OUT + (((size_t)bt * V + i0) * V) + tid;
#pragma unroll
    for (int r = 0; r < CHUNK; ++r)
        obase[(size_t)r * V] = tmp[r] * rden[r];
}

extern "C" void kernel_launch(void* const* d_in, const int* in_sizes, int n_in,
                              void* d_out, int out_size, void* d_ws, size_t ws_size,
                              hipStream_t stream)
{
    const float* X = (const float*)d_in[0];   // [B,T,V,F] fp32
    const float* A = (const float*)d_in[1];   // [F,1]     fp32
    float* OUT = (float*)d_out;               // [B,T,V,V] fp32

    dim3 grid(BT * NCHUNK), block(256);
    gl_fused<<<grid, block, 0, stream>>>(X, A, OUT);
}

// Round 3
// 88.916 us; speedup vs baseline: 1.1436x; 1.1436x over previous
//
#include <hip/hip_runtime.h>

// Problem constants (fixed by reference)
constexpr int B = 4, T = 8, V = 256, F = 64;
constexpr int BT = B * T;            // 32 (b,t) slices
constexpr int CHUNK = 8;             // rows of i per block (proven sweet spot)
constexpr int NCHUNK = V / CHUNK;    // 32 -> grid = 32*32 = 1024 blocks (4 blocks/CU)
constexpr int K4 = F / 4;            // 16 float4 chunks per row

typedef float v2f __attribute__((ext_vector_type(2)));

// Block = (bt, 8-row chunk). Thread tid owns column j=tid.
// score(i,j) = sum_f |x_i[f]-x_j[f]|*a[f] is SYMMETRIC, so denom[i]
// (= column-i sum in the reference) equals the row-i sum -> block-local
// reduction, no grid sync / atomics / workspace.
//
// R6: packed-f32 inner loop (v_pk_sub / v_pk_max(neg) / v_pk_fma).
// R7 (REVERTED): transposed column stream: neutral -> column loads not the
//   bottleneck.
// R8 (REVERTED): launch_bounds(,8) -> VGPR=32 -> load pipeline destroyed,
//   gl_fused 25->50us. Occupancy was never the constraint; load-wait is.
// R9: rows OFF the SMEM path. s_load results return OUT-OF-ORDER on gfx9
//   lineage, so every use forces s_waitcnt lgkmcnt(0) draining the whole
//   scalar queue -> the 128 in-loop s_loads serialized the loop (the ~90%
//   stall). Row i's data IS column i's data, which thread i already loads:
//   threads i0..i0+7 dump their column regs into a 2KB LDS rowbuf once;
//   inner loop reads rows via uniform-address ds_read_b128 (broadcast,
//   conflict-free, in-order, finely-countable lgkmcnt -> pipelineable).
//   'a' hoisted to regs before the loop (one SMEM drain at start).
__global__ __launch_bounds__(256)
void gl_fused(const float* __restrict__ X, const float* __restrict__ A,
              float* __restrict__ OUT)
{
    const int tid = threadIdx.x;           // column j
    const int bt  = blockIdx.x / NCHUNK;
    const int ic  = blockIdx.x % NCHUNK;
    const int i0  = ic * CHUNK;

    const float* xbt = X + (size_t)bt * V * F;            // [256][64] tile

    __shared__ float4 rowbuf[CHUNK][K4];   // 2KB: rows i0..i0+7, feature float4s
    __shared__ float wpart[4][CHUNK];      // per-wave partial row sums
    __shared__ float rden[CHUNK];          // reciprocal denominators

    // a -> one up-front SMEM burst, then register/SGPR resident (loop-invariant)
    float4 areg[K4];
#pragma unroll
    for (int k = 0; k < K4; ++k)
        areg[k] = reinterpret_cast<const float4*>(A)[k];

    // own column -> registers (16 coalesced dwordx4, one vmcnt drain)
    float4 colv[K4];
    const float4* colp = reinterpret_cast<const float4*>(xbt + (size_t)tid * F);
#pragma unroll
    for (int k = 0; k < K4; ++k)
        colv[k] = colp[k];

    // stage this block's rows from the threads that already hold them
    const unsigned r0 = (unsigned)(tid - i0);
    if (r0 < CHUNK) {
#pragma unroll
        for (int k = 0; k < K4; ++k)
            rowbuf[r0][k] = colv[k];
    }
    __syncthreads();

    v2f acc2[CHUNK];
#pragma unroll
    for (int r = 0; r < CHUNK; ++r) acc2[r] = (v2f){0.0f, 0.0f};

#pragma unroll
    for (int k = 0; k < K4; ++k) {
        const float4 xv = colv[k];
        const float4 av = areg[k];
        const v2f xlo = (v2f){xv.x, xv.y};
        const v2f xhi = (v2f){xv.z, xv.w};
        const v2f alo = (v2f){av.x, av.y};
        const v2f ahi = (v2f){av.z, av.w};
#pragma unroll
        for (int r = 0; r < CHUNK; ++r) {
            const float4 sr = rowbuf[r][k];             // ds_read_b128 broadcast
            const v2f d0 = xlo - (v2f){sr.x, sr.y};     // v_pk_add (neg mod)
            const v2f d1 = xhi - (v2f){sr.z, sr.w};
            const v2f a0 = __builtin_elementwise_max(d0, -d0);  // v_pk_max (neg mod)
            const v2f a1 = __builtin_elementwise_max(d1, -d1);
            acc2[r] = __builtin_elementwise_fma(a0, alo, acc2[r]); // v_pk_fma
            acc2[r] = __builtin_elementwise_fma(a1, ahi, acc2[r]);
        }
    }

    float tmp[CHUNK];
#pragma unroll
    for (int r = 0; r < CHUNK; ++r) {
        const float s = acc2[r].x + acc2[r].y;
        tmp[r] = __expf(fmaxf(s, 0.0f));
    }

    // block reduction: row sum = denominator (symmetry)
    const int lane = tid & 63;
    const int wv   = tid >> 6;
#pragma unroll
    for (int r = 0; r < CHUNK; ++r) {
        float v = tmp[r];
        v += __shfl_xor(v, 32);
        v += __shfl_xor(v, 16);
        v += __shfl_xor(v, 8);
        v += __shfl_xor(v, 4);
        v += __shfl_xor(v, 2);
        v += __shfl_xor(v, 1);
        if (lane == 0) wpart[wv][r] = v;
    }
    __syncthreads();
    if (tid < CHUNK) {
        const float d = wpart[0][tid] + wpart[1][tid] + wpart[2][tid] + wpart[3][tid];
        rden[tid] = 1.0f / d;
    }
    __syncthreads();

    // S[bt, i0+r, tid] = tmp[r] / denom[i0+r]; consecutive tids -> coalesced
    float* obase = OUT + (((size_t)bt * V + i0) * V) + tid;
#pragma unroll
    for (int r = 0; r < CHUNK; ++r)
        obase[(size_t)r * V] = tmp[r] * rden[r];
}

extern "C" void kernel_launch(void* const* d_in, const int* in_sizes, int n_in,
                              void* d_out, int out_size, void* d_ws, size_t ws_size,
                              hipStream_t stream)
{
    const float* X = (const float*)d_in[0];   // [B,T,V,F] fp32
    const float* A = (const float*)d_in[1];   // [F,1]     fp32
    float* OUT = (float*)d_out;               // [B,T,V,V] fp32

    dim3 grid(BT * NCHUNK), block(256);
    gl_fused<<<grid, block, 0, stream>>>(X, A, OUT);
}

// Round 4
// 71.850 us; speedup vs baseline: 1.4152x; 1.2375x over previous
//
#include <hip/hip_runtime.h>

// Problem constants (fixed by reference)
constexpr int B = 4, T = 8, V = 256, F = 64;
constexpr int BT = B * T;            // 32 (b,t) slices
constexpr int CHUNK = 8;             // rows of i per block (proven sweet spot)
constexpr int NCHUNK = V / CHUNK;    // 32 -> grid = 32*32 = 1024 blocks (4 blocks/CU)
constexpr int NXCD = 8;

typedef float v2f __attribute__((ext_vector_type(2)));

// Block = (bt, 8-row chunk). Thread tid owns column j=tid.
// score(i,j) = sum_f |x_i[f]-x_j[f]|*a[f] is SYMMETRIC, so denom[i]
// (= column-i sum in the reference) equals the row-i sum -> block-local
// reduction, no grid sync / atomics / workspace.
//
// R5: row data via WAVE-UNIFORM global addresses -> s_load_dwordx4.
// R6: packed-f32 inner loop (v_pk_sub / v_pk_max(neg) / v_pk_fma).
// R7 (REVERTED): transpose copy — neutral: the xpose kernel paid the same
//   cold-HBM amplification it removed from gl_fused.
// R8 (REVERTED): launch_bounds(,8) -> VGPR=32 destroyed the load pipeline.
// R9 (REVERTED): LDS rowbuf + hoisted a/col regs -> 128+ VGPRs, LDS-pipe
//   issue cost; kernel 21 -> ~38us.
// R10: THE bottleneck (R8's gl_fused PMC row): FETCH_SIZE=48.8MB vs 2MB of
//   X = 24x HBM over-fetch at ~2.3 TB/s effective (contending with the
//   256MiB fill's writeback, which also cold-evicts L2/L3 every iteration)
//   = ~21us — matches the kernel time. Fix: bijective chunked XCD swizzle.
//   Launched block b lands on XCD b%8; remap to logical (b%8)*128 + b/8 so
//   each XCD owns 4 whole bt-slices (256KB, L2-resident) and its 128 blocks
//   are co-resident (4/CU x 32CU) -> each slice fetched from HBM ~once.
__global__ __launch_bounds__(256)
void gl_fused(const float* __restrict__ X, const float* __restrict__ A,
              float* __restrict__ OUT)
{
    const int tid = threadIdx.x;           // column j
    // XCD swizzle: consecutive logical blocks (same bt) pinned to one XCD
    const int lb  = (blockIdx.x & (NXCD - 1)) * (BT * NCHUNK / NXCD)
                  + (blockIdx.x >> 3);
    const int bt  = lb >> 5;               // / NCHUNK
    const int ic  = lb & (NCHUNK - 1);
    const int i0  = ic * CHUNK;

    const float* xbt = X + (size_t)bt * V * F;            // [256][64] tile
    const float4* xrow4 = reinterpret_cast<const float4*>(xbt + (size_t)i0 * F);
    // xrow4[r*(F/4) + k] = float4 of row i0+r, features 4k..4k+3 (uniform addr)

    __shared__ float wpart[4][CHUNK];      // per-wave partial row sums
    __shared__ float rden[CHUNK];          // reciprocal denominators

    // a -> uniform address, scalarized; keep as packed pairs
    v2f af2[F / 2];
#pragma unroll
    for (int k = 0; k < F / 4; ++k) {
        const float4 v = reinterpret_cast<const float4*>(A)[k];
        af2[2*k+0] = (v2f){v.x, v.y};
        af2[2*k+1] = (v2f){v.z, v.w};
    }

    v2f acc2[CHUNK];
#pragma unroll
    for (int r = 0; r < CHUNK; ++r) acc2[r] = (v2f){0.0f, 0.0f};

    // stream own column in float4 chunks; CHUNK independent packed fma chains.
    const float4* colp = reinterpret_cast<const float4*>(xbt + (size_t)tid * F);
#pragma unroll
    for (int k = 0; k < F / 4; ++k) {
        const float4 xv = colp[k];
        const v2f xlo = (v2f){xv.x, xv.y};
        const v2f xhi = (v2f){xv.z, xv.w};
#pragma unroll
        for (int r = 0; r < CHUNK; ++r) {
            const float4 sr = xrow4[r * (F / 4) + k];   // uniform -> s_load_dwordx4
            const v2f d0 = xlo - (v2f){sr.x, sr.y};     // v_pk_add (neg mod)
            const v2f d1 = xhi - (v2f){sr.z, sr.w};
            const v2f a0 = __builtin_elementwise_max(d0, -d0);  // v_pk_max (neg mod)
            const v2f a1 = __builtin_elementwise_max(d1, -d1);
            acc2[r] = __builtin_elementwise_fma(a0, af2[2*k+0], acc2[r]); // v_pk_fma
            acc2[r] = __builtin_elementwise_fma(a1, af2[2*k+1], acc2[r]);
        }
    }

    float tmp[CHUNK];
#pragma unroll
    for (int r = 0; r < CHUNK; ++r) {
        const float s = acc2[r].x + acc2[r].y;
        tmp[r] = __expf(fmaxf(s, 0.0f));
    }

    // block reduction: row sum = denominator (symmetry)
    const int lane = tid & 63;
    const int wv   = tid >> 6;
#pragma unroll
    for (int r = 0; r < CHUNK; ++r) {
        float v = tmp[r];
        v += __shfl_xor(v, 32);
        v += __shfl_xor(v, 16);
        v += __shfl_xor(v, 8);
        v += __shfl_xor(v, 4);
        v += __shfl_xor(v, 2);
        v += __shfl_xor(v, 1);
        if (lane == 0) wpart[wv][r] = v;
    }
    __syncthreads();
    if (tid < CHUNK) {
        const float d = wpart[0][tid] + wpart[1][tid] + wpart[2][tid] + wpart[3][tid];
        rden[tid] = 1.0f / d;
    }
    __syncthreads();

    // S[bt, i0+r, tid] = tmp[r] / denom[i0+r]; consecutive tids -> coalesced
    float* obase = OUT + (((size_t)bt * V + i0) * V) + tid;
#pragma unroll
    for (int r = 0; r < CHUNK; ++r)
        obase[(size_t)r * V] = tmp[r] * rden[r];
}

extern "C" void kernel_launch(void* const* d_in, const int* in_sizes, int n_in,
                              void* d_out, int out_size, void* d_ws, size_t ws_size,
                              hipStream_t stream)
{
    const float* X = (const float*)d_in[0];   // [B,T,V,F] fp32
    const float* A = (const float*)d_in[1];   // [F,1]     fp32
    float* OUT = (float*)d_out;               // [B,T,V,V] fp32

    dim3 grid(BT * NCHUNK), block(256);
    gl_fused<<<grid, block, 0, stream>>>(X, A, OUT);
}